// Round 1
// baseline (206.232 us; speedup 1.0000x reference)
//
#include <hip/hip_runtime.h>

// Gray-Scott PDE residual, 4-way T-split t-march, float4/thread,
// nontemporal output stores, XCD-pinned batches.
//   in  : (T=20, B=8, C=3, H=256, W=256) fp32; u = ch1, v = ch2
//   out : [f_u | f_v], each (20,8,1,252,252) fp32
//
// R1 change vs R0 baseline: the full-20-step march gave only 504 blocks
// (1.97 waves/SIMD) -- latency-starved at 13% of achievable HBM BW.
// Split t into 4 chunks of 5 output steps (each chunk reads 2 extra halo
// planes: 26 planes vs 20, +30% reads, +15% total traffic) -> 2016 blocks
// = 7.9 waves/SIMD of work, __launch_bounds__(256,4) to keep 4 blocks/CU
// resident. Each thread owns 4 x-outputs of one (b,y) row and marches its
// chunk with rolling registers (c_{t-2}, c_{t-1}, c_t, lap_{t-1}).

#define T_OUT (8 * 252 * 252)

typedef float vf4 __attribute__((ext_vector_type(4)));

static __device__ __forceinline__ vf4 ldu4(const float* p) {
    vf4 v;
    __builtin_memcpy(&v, p, 16);   // 8B-aligned 16B load; gfx950 handles it
    return v;
}

#define GS_INT(c) { \
    float ut = (ucn.c - u_cm1.c) * hdt; \
    float vt = (vcn.c - v_cm1.c) * hdt; \
    float uvv = u_cc.c * v_cc.c * v_cc.c; \
    fu.c = Du * u_lm1.c - uvv + fR * (1.0f - u_cc.c) - ut; \
    fv.c = Dv * v_lm1.c + uvv - (fR + kR) * v_cc.c - vt; }

#define GS_T0(c) { \
    float ut = (-1.5f * u_cm1.c + 2.0f * u_cc.c - 0.5f * ucn.c) * inv_dt; \
    float vt = (-1.5f * v_cm1.c + 2.0f * v_cc.c - 0.5f * vcn.c) * inv_dt; \
    float uvv = u_cm1.c * v_cm1.c * v_cm1.c; \
    fu.c = Du * u_l0.c - uvv + fR * (1.0f - u_cm1.c) - ut; \
    fv.c = Dv * v_l0.c + uvv - (fR + kR) * v_cm1.c - vt; }

#define GS_TN(c) { \
    float ut = (0.5f * u_cm2.c - 2.0f * u_cm1.c + 1.5f * u_cc.c) * inv_dt; \
    float vt = (0.5f * v_cm2.c - 2.0f * v_cm1.c + 1.5f * v_cc.c) * inv_dt; \
    float uvv = u_cc.c * v_cc.c * v_cc.c; \
    fu.c = Du * u_lm1.c - uvv + fR * (1.0f - u_cc.c) - ut; \
    fv.c = Dv * v_lm1.c + uvv - (fR + kR) * v_cc.c - vt; }

__global__ __launch_bounds__(256, 4) void gs_loss_kernel(
    const float* __restrict__ in, float* __restrict__ out)
{
    const int tid  = threadIdx.x;
    const int xg   = tid & 63;          // 63 active x-groups of 4
    const int yloc = tid >> 6;          // 0..3
    if (xg >= 63) return;

    const int b     = blockIdx.x & 7;   // batch -> XCD pinning
    const int rest  = blockIdx.x >> 3;  // 0..251
    const int chunk = rest & 3;         // t-chunk: low bits so all chunks
                                        // run concurrently from dispatch 0
    const int ytile = rest >> 2;        // 0..62

    const int y  = ytile * 4 + yloc;    // 0..251
    const int x0 = xg * 4;              // 16B-aligned plane column

    // chunk c emits outputs s in [5c, 5c+5); rolling march needs planes
    // t = 5c-1 .. 5c+5 (one-sided edges for chunk 0 / chunk 3).
    const int ts = (chunk == 0) ? 0  : 5 * chunk - 1;
    const int te = (chunk == 3) ? 19 : 5 * chunk + 5;

    const int planeStride = 256 * 256;
    const int bStride     = 3 * planeStride;
    const int tStride     = 8 * bStride;

    // u-plane (ch1) address of row y+2, col x0 (centers at cols x0+2..x0+5)
    const float* ubase = in + (size_t)b * bStride + planeStride
                         + (size_t)(y + 2) * 256 + x0;

    const int total = 20 * T_OUT;
    float* outu = out + ((size_t)b * 252 + y) * 252 + x0;
    float* outv = outu + total;

    const float C1 = 4.0f / 3.0f, C2 = 1.0f / 12.0f;
    const float inv_dx2 = 1.0f / (0.15625f * 0.15625f);   // DX = 20/128
    const float inv_dt  = 20.0f;                          // 1/DT
    const float hdt     = 10.0f;                          // 1/(2 DT)
    const float Du = 0.16f, Dv = 0.08f, fR = 0.06f, kR = 0.062f;

    vf4 u_cm2{}, u_cm1{}, u_cc{}, u_lm1{}, u_l0{};
    vf4 v_cm2{}, v_cm1{}, v_cc{}, v_lm1{}, v_l0{};

    for (int t = ts; t <= te; ++t) {
        const float* up = ubase + (size_t)t * tStride;
        const float* vp = up + planeStride;

        // center row: cols x0..x0+7 as two aligned 16B loads
        vf4 uL = *(const vf4*)(up);
        vf4 uR = *(const vf4*)(up + 4);
        // halo rows: cols x0+2..x0+5 as one (8B-aligned) 16B load each
        vf4 um1 = ldu4(up - 256 + 2);
        vf4 up1 = ldu4(up + 256 + 2);
        vf4 um2 = ldu4(up - 512 + 2);
        vf4 up2 = ldu4(up + 512 + 2);

        vf4 vL = *(const vf4*)(vp);
        vf4 vR = *(const vf4*)(vp + 4);
        vf4 vm1 = ldu4(vp - 256 + 2);
        vf4 vp1 = ldu4(vp + 256 + 2);
        vf4 vm2 = ldu4(vp - 512 + 2);
        vf4 vp2 = ldu4(vp + 512 + 2);

        vf4 lu, lv;
        lu.x = (C1*(uL.y + uL.w + um1.x + up1.x) - C2*(uL.x + uR.x + um2.x + up2.x) - 5.0f*uL.z) * inv_dx2;
        lu.y = (C1*(uL.z + uR.x + um1.y + up1.y) - C2*(uL.y + uR.y + um2.y + up2.y) - 5.0f*uL.w) * inv_dx2;
        lu.z = (C1*(uL.w + uR.y + um1.z + up1.z) - C2*(uL.z + uR.z + um2.z + up2.z) - 5.0f*uR.x) * inv_dx2;
        lu.w = (C1*(uR.x + uR.z + um1.w + up1.w) - C2*(uL.w + uR.w + um2.w + up2.w) - 5.0f*uR.y) * inv_dx2;
        lv.x = (C1*(vL.y + vL.w + vm1.x + vp1.x) - C2*(vL.x + vR.x + vm2.x + vp2.x) - 5.0f*vL.z) * inv_dx2;
        lv.y = (C1*(vL.z + vR.x + vm1.y + vp1.y) - C2*(vL.y + vR.y + vm2.y + vp2.y) - 5.0f*vL.w) * inv_dx2;
        lv.z = (C1*(vL.w + vR.y + vm1.z + vp1.z) - C2*(vL.z + vR.z + vm2.z + vp2.z) - 5.0f*vR.x) * inv_dx2;
        lv.w = (C1*(vR.x + vR.z + vm1.w + vp1.w) - C2*(vL.w + vR.w + vm2.w + vp2.w) - 5.0f*vR.y) * inv_dx2;

        vf4 ucn = {uL.z, uL.w, uR.x, uR.y};   // centers at t
        vf4 vcn = {vL.z, vL.w, vR.x, vR.y};

        if (t == 0) { u_l0 = lu; v_l0 = lv; }   // only reachable for chunk 0

        if (t == 2) {
            // emit t=0 one-sided: c0=cm1, c1=cc, c2=ucn, lap=l0 (chunk 0 only)
            vf4 fu, fv;
            GS_T0(x); GS_T0(y); GS_T0(z); GS_T0(w);
            __builtin_nontemporal_store(fu, (vf4*)(outu));
            __builtin_nontemporal_store(fv, (vf4*)(outv));
        }

        if (t >= ts + 2) {
            // emit t-1 interior: center=cc, u_t=(c_t - c_{t-2})/(2DT), lap=lm1
            vf4 fu, fv;
            GS_INT(x); GS_INT(y); GS_INT(z); GS_INT(w);
            __builtin_nontemporal_store(fu, (vf4*)(outu + (size_t)(t - 1) * T_OUT));
            __builtin_nontemporal_store(fv, (vf4*)(outv + (size_t)(t - 1) * T_OUT));
        }

        u_cm2 = u_cm1; u_cm1 = u_cc; u_cc = ucn; u_lm1 = lu;
        v_cm2 = v_cm1; v_cm1 = v_cc; v_cc = vcn; v_lm1 = lv;
    }

    if (chunk == 3) {
        // emit t=19 one-sided: c17=cm2, c18=cm1, c19=cc, lap19=lm1
        vf4 fu, fv;
        GS_TN(x); GS_TN(y); GS_TN(z); GS_TN(w);
        __builtin_nontemporal_store(fu, (vf4*)(outu + (size_t)19 * T_OUT));
        __builtin_nontemporal_store(fv, (vf4*)(outv + (size_t)19 * T_OUT));
    }
}

extern "C" void kernel_launch(void* const* d_in, const int* in_sizes, int n_in,
                              void* d_out, int out_size, void* d_ws, size_t ws_size,
                              hipStream_t stream) {
    const float* in = (const float*)d_in[0];
    float* out = (float*)d_out;

    // 4 t-chunks * 63 y-tiles * 8 b = 2016 blocks of 256 threads
    // (~7.9 blocks/CU of work, 4 resident via __launch_bounds__(256,4))
    gs_loss_kernel<<<4 * 8 * 63, 256, 0, stream>>>(in, out);
}